// Round 4
// baseline (2042.928 us; speedup 1.0000x reference)
//
#include <hip/hip_runtime.h>
#include <stdint.h>
#include <stddef.h>

typedef unsigned short ushort_t;
typedef __attribute__((ext_vector_type(8))) unsigned short us8;
typedef __attribute__((ext_vector_type(4))) unsigned short us4;
typedef __attribute__((ext_vector_type(8))) short bf16x8;
typedef __attribute__((ext_vector_type(4))) float f32x4;
typedef __attribute__((ext_vector_type(4))) float f4;

#define DM 1024
#define SEQ 2048
#define NBATCH 2
#define NHEADS 16
#define HDIM 64
#define DH 4096
#define ROWS 4096  // NBATCH*SEQ

__device__ __forceinline__ float bf2f(ushort_t u) {
  union { unsigned int i; float f; } v; v.i = ((unsigned int)u) << 16; return v.f;
}
__device__ __forceinline__ ushort_t f2bf(float f) {
  union { float f; unsigned int i; } v; v.f = f;
  unsigned int x = v.i;
  unsigned int r = (x + 0x7FFFu + ((x >> 16) & 1u)) >> 16;  // RNE
  return (ushort_t)r;
}

// ---------------- fp32 -> bf16 bulk convert (weights) ----------------
__global__ void f32_to_bf16(const float* __restrict__ in,
                            ushort_t* __restrict__ out, int n) {
  int i = (blockIdx.x * 256 + threadIdx.x) * 4;
  if (i >= n) return;
  f4 v = *(const f4*)(in + i);
  us4 o;
#pragma unroll
  for (int j = 0; j < 4; ++j) o[j] = f2bf(v[j]);
  *(us4*)(out + i) = o;
}

// ---------------- RMSNorm: y = bf16( w * x * rsqrt(mean(x^2)+1e-6) ) ----------------
// x, w fp32; y bf16
__global__ void rmsnorm_kernel(const float* __restrict__ x,
                               const float* __restrict__ w,
                               ushort_t* __restrict__ y) {
  int row = blockIdx.x;
  int t = threadIdx.x;
  f4 xv = *(const f4*)(x + (size_t)row * DM + t * 4);
  float s = 0.f;
#pragma unroll
  for (int j = 0; j < 4; ++j) s += xv[j] * xv[j];
#pragma unroll
  for (int off = 32; off >= 1; off >>= 1) s += __shfl_xor(s, off);
  __shared__ float wsum[4];
  if ((t & 63) == 0) wsum[t >> 6] = s;
  __syncthreads();
  float tot = wsum[0] + wsum[1] + wsum[2] + wsum[3];
  float scale = rsqrtf(tot * (1.0f / DM) + 1e-6f);
  f4 wv = *(const f4*)(w + t * 4);
  us4 o;
#pragma unroll
  for (int j = 0; j < 4; ++j) o[j] = f2bf(xv[j] * wv[j] * scale);
  *(us4*)(y + (size_t)row * DM + t * 4) = o;
}

// ---- MFMA bf16 GEMM: C[MxN] = A[MxK] @ B[KxN], A,B bf16, B native K x N ----
// B transposed into LDS during staging with XOR-swizzled k index (bits 3..5):
// 8-lane scatter group hits 8 distinct banks; fragment 8-chunks stay contiguous.
// EPI 0: C(bf16) = acc
// EPI 1: C(fp32) = acc + bias(fp32)[col] + res(fp32)[row,col]
// EPI 2: C(bf16) = silu(res(bf16)) * acc
#define LDKP 72

template <int EPI>
__global__ __launch_bounds__(256) void gemm_nt(
    const ushort_t* __restrict__ A, const ushort_t* __restrict__ B,
    void* __restrict__ Cv, int M, int N, int K,
    const float* __restrict__ bias, const void* __restrict__ resv) {
  __shared__ __align__(16) ushort_t As[128 * LDKP];
  __shared__ __align__(16) ushort_t Bs[128 * LDKP];
  int tid = threadIdx.x;
  int l = tid & 63;
  int w = tid >> 6;
  int wm = w >> 1, wn = w & 1;
  int m0 = blockIdx.y * 128;
  int n0 = blockIdx.x * 128;
  int lr = l & 15;
  int lk = (l >> 4) * 8;
  f32x4 acc[4][4] = {};

  const ushort_t* Ag = A + (size_t)m0 * K;

  for (int kt = 0; kt < K; kt += 64) {
    // A staging: 128 rows x 64 k, vectorized
#pragma unroll
    for (int i = 0; i < 4; ++i) {
      int c = i * 256 + tid;
      int row = c >> 3, col8 = (c & 7) * 8;
      *(us8*)(&As[row * LDKP + col8]) =
          *(const us8*)(Ag + (size_t)row * K + kt + col8);
    }
    // B staging: 64 k-rows x 128 n-cols, transposed into Bs[n][k ^ swz(n)]
#pragma unroll
    for (int i = 0; i < 4; ++i) {
      int c = i * 256 + tid;
      int kr = c >> 4;              // 0..63
      int nc = (c & 15) * 8;        // 0..120 (multiple of 8)
      us8 v = *(const us8*)(B + (size_t)(kt + kr) * N + n0 + nc);
      int kcol = kr ^ (((nc >> 3) & 7) << 3);
#pragma unroll
      for (int j = 0; j < 8; ++j)
        Bs[(nc + j) * LDKP + kcol] = v[j];
    }
    __syncthreads();
#pragma unroll
    for (int kk = 0; kk < 2; ++kk) {
      bf16x8 a[4], b[4];
#pragma unroll
      for (int i = 0; i < 4; ++i) {
        a[i] = *(const bf16x8*)(&As[(wm * 64 + i * 16 + lr) * LDKP + kk * 32 + lk]);
        int bn = wn * 64 + i * 16 + lr;
        int bko = (kk * 32 + lk) ^ (((bn >> 3) & 7) << 3);
        b[i] = *(const bf16x8*)(&Bs[bn * LDKP + bko]);
      }
#pragma unroll
      for (int i = 0; i < 4; ++i)
#pragma unroll
        for (int j = 0; j < 4; ++j)
          acc[i][j] = __builtin_amdgcn_mfma_f32_16x16x32_bf16(a[i], b[j], acc[i][j], 0, 0, 0);
    }
    __syncthreads();
  }

  int r0 = (l >> 4) * 4;
#pragma unroll
  for (int i = 0; i < 4; ++i) {
#pragma unroll
    for (int r = 0; r < 4; ++r) {
      int grow = m0 + wm * 64 + i * 16 + r0 + r;
#pragma unroll
      for (int j = 0; j < 4; ++j) {
        int gcol = n0 + wn * 64 + j * 16 + lr;
        size_t idx = (size_t)grow * N + gcol;
        float v = acc[i][j][r];
        if (EPI == 0) {
          ((ushort_t*)Cv)[idx] = f2bf(v);
        } else if (EPI == 1) {
          float r2 = ((const float*)resv)[idx];
          ((float*)Cv)[idx] = v + bias[gcol] + r2;
        } else {
          float g = bf2f(((const ushort_t*)resv)[idx]);
          ((ushort_t*)Cv)[idx] = f2bf(v * g / (1.0f + __expf(-g)));
        }
      }
    }
  }
}

// ---------------- attention: per-wave 8 query rows, two-pass recompute ----------------
// layout: Q/K/V/O all (b, l, d) bf16 with head h occupying cols [h*64, h*64+64)
__global__ __launch_bounds__(256) void attn_kernel(
    const ushort_t* __restrict__ Qp, const ushort_t* __restrict__ Kp,
    const ushort_t* __restrict__ Vp, ushort_t* __restrict__ Op) {
  int tid = threadIdx.x;
  int l = tid & 63;
  int w = tid >> 6;
  int jj = l >> 3, ds = l & 7;
  int h = blockIdx.y, b = blockIdx.z;
  int qr = blockIdx.x * 32 + w * 8;  // 8 rows per wave
  const size_t base = (size_t)b * SEQ * DM + h * HDIM;

  float q[8][8];
#pragma unroll
  for (int r = 0; r < 8; ++r) {
    us8 v = *(const us8*)(Qp + base + (size_t)(qr + r) * DM + ds * 8);
#pragma unroll
    for (int t = 0; t < 8; ++t) q[r][t] = bf2f(v[t]) * 0.125f;  // fold 1/sqrt(64)
  }

  float mx[8];
#pragma unroll
  for (int r = 0; r < 8; ++r) mx[r] = -1e30f;

  // pass A: per-jj-class max of scores
  for (int j0 = 0; j0 < SEQ; j0 += 8) {
    us8 kv = *(const us8*)(Kp + base + (size_t)(j0 + jj) * DM + ds * 8);
    float kf[8];
#pragma unroll
    for (int t = 0; t < 8; ++t) kf[t] = bf2f(kv[t]);
#pragma unroll
    for (int r = 0; r < 8; ++r) {
      float s = 0.f;
#pragma unroll
      for (int t = 0; t < 8; ++t) s += q[r][t] * kf[t];
      s += __shfl_xor(s, 1); s += __shfl_xor(s, 2); s += __shfl_xor(s, 4);
      mx[r] = fmaxf(mx[r], s);
    }
  }
#pragma unroll
  for (int r = 0; r < 8; ++r) {
    mx[r] = fmaxf(mx[r], __shfl_xor(mx[r], 8));
    mx[r] = fmaxf(mx[r], __shfl_xor(mx[r], 16));
    mx[r] = fmaxf(mx[r], __shfl_xor(mx[r], 32));
  }

  // pass B: recompute scores, accumulate exp-sum + unnormalized PV
  float acc[8][8] = {};
  float sum[8] = {};
  for (int j0 = 0; j0 < SEQ; j0 += 8) {
    us8 kv = *(const us8*)(Kp + base + (size_t)(j0 + jj) * DM + ds * 8);
    us8 vv = *(const us8*)(Vp + base + (size_t)(j0 + jj) * DM + ds * 8);
    float kf[8], vf[8];
#pragma unroll
    for (int t = 0; t < 8; ++t) { kf[t] = bf2f(kv[t]); vf[t] = bf2f(vv[t]); }
#pragma unroll
    for (int r = 0; r < 8; ++r) {
      float s = 0.f;
#pragma unroll
      for (int t = 0; t < 8; ++t) s += q[r][t] * kf[t];
      s += __shfl_xor(s, 1); s += __shfl_xor(s, 2); s += __shfl_xor(s, 4);
      float p = __expf(s - mx[r]);
      sum[r] += p;
#pragma unroll
      for (int t = 0; t < 8; ++t) acc[r][t] += p * vf[t];
    }
  }

#pragma unroll
  for (int r = 0; r < 8; ++r) {
    float st = sum[r];
    st += __shfl_xor(st, 8); st += __shfl_xor(st, 16); st += __shfl_xor(st, 32);
    float inv = 1.0f / st;
    us8 o;
#pragma unroll
    for (int t = 0; t < 8; ++t) {
      float a = acc[r][t];
      a += __shfl_xor(a, 8); a += __shfl_xor(a, 16); a += __shfl_xor(a, 32);
      o[t] = f2bf(a * inv);
    }
    if (jj == 0)
      *(us8*)(Op + base + (size_t)(qr + r) * DM + ds * 8) = o;
  }
}

// ---------------------------------------------------------------------------
// fp32 I/O per the reference (all jnp.float32). Internals bf16 MFMA.
// Workspace plan (peak 72 MB, bytes):
//   [0,32M):  bf16 weights  Wq@0 Wk@2M Wv@4M Wo@6M Wg@8M Wh@16M Wu@24M
//   [32,40M): hb (bf16 norm output)
//   [40,72M): phase1 qb@40 kb@48 vb@56 ab@64 | phase2 gb@40 (32 MB overlay)
//   x2 lives in d_out (fp32, 16 MB): O-proj writes it, final GEMM updates
//   it in place (per-thread read-then-write on disjoint elements).
extern "C" void kernel_launch(void* const* d_in, const int* in_sizes, int n_in,
                              void* d_out, int out_size, void* d_ws, size_t ws_size,
                              hipStream_t stream) {
  const float* x   = (const float*)d_in[0];
  const float* Wq  = (const float*)d_in[1];
  const float* Wk  = (const float*)d_in[2];
  const float* Wv  = (const float*)d_in[3];
  const float* Wo  = (const float*)d_in[4];
  const float* bo  = (const float*)d_in[5];
  const float* anw = (const float*)d_in[6];
  const float* fnw = (const float*)d_in[7];
  const float* Wg  = (const float*)d_in[8];
  const float* Wh  = (const float*)d_in[9];
  const float* Wu  = (const float*)d_in[10];
  const float* bu  = (const float*)d_in[11];

  char* wsb = (char*)d_ws;
  ushort_t* Wqb = (ushort_t*)(wsb + 0);
  ushort_t* Wkb = (ushort_t*)(wsb + (2u << 20));
  ushort_t* Wvb = (ushort_t*)(wsb + (4u << 20));
  ushort_t* Wob = (ushort_t*)(wsb + (6u << 20));
  ushort_t* Wgb = (ushort_t*)(wsb + (8u << 20));
  ushort_t* Whb = (ushort_t*)(wsb + (16u << 20));
  ushort_t* Wub = (ushort_t*)(wsb + (24u << 20));
  ushort_t* hb  = (ushort_t*)(wsb + (32u << 20));
  ushort_t* qb  = (ushort_t*)(wsb + (40u << 20));
  ushort_t* kb  = (ushort_t*)(wsb + (48u << 20));
  ushort_t* vb  = (ushort_t*)(wsb + (56u << 20));
  ushort_t* ab  = (ushort_t*)(wsb + (64u << 20));
  ushort_t* gb  = (ushort_t*)(wsb + (40u << 20));  // overlays qb..ab (dead)
  float* out = (float*)d_out;

  // weight conversions fp32 -> bf16 (per-launch; no state carryover)
  f32_to_bf16<<<1024, 256, 0, stream>>>(Wq, Wqb, DM * DM);
  f32_to_bf16<<<1024, 256, 0, stream>>>(Wk, Wkb, DM * DM);
  f32_to_bf16<<<1024, 256, 0, stream>>>(Wv, Wvb, DM * DM);
  f32_to_bf16<<<1024, 256, 0, stream>>>(Wo, Wob, DM * DM);
  f32_to_bf16<<<4096, 256, 0, stream>>>(Wg, Wgb, DM * DH);
  f32_to_bf16<<<4096, 256, 0, stream>>>(Wh, Whb, DM * DH);
  f32_to_bf16<<<4096, 256, 0, stream>>>(Wu, Wub, DH * DM);

  // attn branch
  rmsnorm_kernel<<<ROWS, 256, 0, stream>>>(x, anw, hb);
  gemm_nt<0><<<dim3(8, 32), 256, 0, stream>>>(hb, Wqb, qb, ROWS, DM, DM, nullptr, nullptr);
  gemm_nt<0><<<dim3(8, 32), 256, 0, stream>>>(hb, Wkb, kb, ROWS, DM, DM, nullptr, nullptr);
  gemm_nt<0><<<dim3(8, 32), 256, 0, stream>>>(hb, Wvb, vb, ROWS, DM, DM, nullptr, nullptr);
  attn_kernel<<<dim3(SEQ / 32, NHEADS, NBATCH), 256, 0, stream>>>(qb, kb, vb, ab);
  // x2 = x + attn @ Wo + bo  -> d_out (fp32)
  gemm_nt<1><<<dim3(8, 32), 256, 0, stream>>>(ab, Wob, out, ROWS, DM, DM, bo, x);

  // ffn branch
  rmsnorm_kernel<<<ROWS, 256, 0, stream>>>(out, fnw, hb);  // h2 (bf16)
  gemm_nt<0><<<dim3(32, 32), 256, 0, stream>>>(hb, Wgb, gb, ROWS, DH, DM, nullptr, nullptr);
  // act = silu(gate) * (h2 @ Wh), fused epilogue, in-place into gb
  gemm_nt<2><<<dim3(32, 32), 256, 0, stream>>>(hb, Whb, gb, ROWS, DH, DM, nullptr, gb);
  // out = x2 + act @ Wu + bu  (res = d_out, in-place, fp32)
  gemm_nt<1><<<dim3(8, 32), 256, 0, stream>>>(gb, Wub, out, ROWS, DM, DH, bu, out);
}

// Round 5
// 535.748 us; speedup vs baseline: 3.8132x; 3.8132x over previous
//
#include <hip/hip_runtime.h>
#include <stdint.h>
#include <stddef.h>

typedef unsigned short ushort_t;
typedef __attribute__((ext_vector_type(8))) unsigned short us8;
typedef __attribute__((ext_vector_type(4))) unsigned short us4;
typedef __attribute__((ext_vector_type(2))) unsigned int u32x2;
typedef __attribute__((ext_vector_type(8))) short bf16x8;
typedef __attribute__((ext_vector_type(4))) float f32x4;
typedef __attribute__((ext_vector_type(4))) float f4;

#define DM 1024
#define SEQ 2048
#define NBATCH 2
#define NHEADS 16
#define HDIM 64
#define DH 4096
#define ROWS 4096  // NBATCH*SEQ

__device__ __forceinline__ float bf2f(ushort_t u) {
  union { unsigned int i; float f; } v; v.i = ((unsigned int)u) << 16; return v.f;
}
__device__ __forceinline__ ushort_t f2bf(float f) {
  union { float f; unsigned int i; } v; v.f = f;
  unsigned int x = v.i;
  unsigned int r = (x + 0x7FFFu + ((x >> 16) & 1u)) >> 16;  // RNE
  return (ushort_t)r;
}

// ---------------- fp32 -> bf16 bulk convert (weights) ----------------
__global__ void f32_to_bf16(const float* __restrict__ in,
                            ushort_t* __restrict__ out, int n) {
  int i = (blockIdx.x * 256 + threadIdx.x) * 4;
  if (i >= n) return;
  f4 v = *(const f4*)(in + i);
  us4 o;
#pragma unroll
  for (int j = 0; j < 4; ++j) o[j] = f2bf(v[j]);
  *(us4*)(out + i) = o;
}

// ---------------- RMSNorm: y = bf16( w * x * rsqrt(mean(x^2)+1e-6) ) ----------------
__global__ void rmsnorm_kernel(const float* __restrict__ x,
                               const float* __restrict__ w,
                               ushort_t* __restrict__ y) {
  int row = blockIdx.x;
  int t = threadIdx.x;
  f4 xv = *(const f4*)(x + (size_t)row * DM + t * 4);
  float s = 0.f;
#pragma unroll
  for (int j = 0; j < 4; ++j) s += xv[j] * xv[j];
#pragma unroll
  for (int off = 32; off >= 1; off >>= 1) s += __shfl_xor(s, off);
  __shared__ float wsum[4];
  if ((t & 63) == 0) wsum[t >> 6] = s;
  __syncthreads();
  float tot = wsum[0] + wsum[1] + wsum[2] + wsum[3];
  float scale = rsqrtf(tot * (1.0f / DM) + 1e-6f);
  f4 wv = *(const f4*)(w + t * 4);
  us4 o;
#pragma unroll
  for (int j = 0; j < 4; ++j) o[j] = f2bf(xv[j] * wv[j] * scale);
  *(us4*)(y + (size_t)row * DM + t * 4) = o;
}

// ---- MFMA bf16 GEMM: C[MxN] = A[MxK] @ B[KxN], A,B bf16, B native K x N ----
// EPI 0: C(bf16)=acc; 1: C(fp32)=acc+bias+res(fp32); 2: C(bf16)=silu(res(bf16))*acc
#define LDKP 72

template <int EPI>
__global__ __launch_bounds__(256) void gemm_nt(
    const ushort_t* __restrict__ A, const ushort_t* __restrict__ B,
    void* __restrict__ Cv, int M, int N, int K,
    const float* __restrict__ bias, const void* __restrict__ resv) {
  __shared__ __align__(16) ushort_t As[128 * LDKP];
  __shared__ __align__(16) ushort_t Bs[128 * LDKP];
  int tid = threadIdx.x;
  int l = tid & 63;
  int w = tid >> 6;
  int wm = w >> 1, wn = w & 1;
  int m0 = blockIdx.y * 128;
  int n0 = blockIdx.x * 128;
  int lr = l & 15;
  int lk = (l >> 4) * 8;
  f32x4 acc[4][4] = {};

  const ushort_t* Ag = A + (size_t)m0 * K;

  for (int kt = 0; kt < K; kt += 64) {
#pragma unroll
    for (int i = 0; i < 4; ++i) {
      int c = i * 256 + tid;
      int row = c >> 3, col8 = (c & 7) * 8;
      *(us8*)(&As[row * LDKP + col8]) =
          *(const us8*)(Ag + (size_t)row * K + kt + col8);
    }
#pragma unroll
    for (int i = 0; i < 4; ++i) {
      int c = i * 256 + tid;
      int kr = c >> 4;              // 0..63
      int nc = (c & 15) * 8;        // 0..120
      us8 v = *(const us8*)(B + (size_t)(kt + kr) * N + n0 + nc);
      int kcol = kr ^ (((nc >> 3) & 7) << 3);
#pragma unroll
      for (int j = 0; j < 8; ++j)
        Bs[(nc + j) * LDKP + kcol] = v[j];
    }
    __syncthreads();
#pragma unroll
    for (int kk = 0; kk < 2; ++kk) {
      bf16x8 a[4], b[4];
#pragma unroll
      for (int i = 0; i < 4; ++i) {
        a[i] = *(const bf16x8*)(&As[(wm * 64 + i * 16 + lr) * LDKP + kk * 32 + lk]);
        int bn = wn * 64 + i * 16 + lr;
        int bko = (kk * 32 + lk) ^ (((bn >> 3) & 7) << 3);
        b[i] = *(const bf16x8*)(&Bs[bn * LDKP + bko]);
      }
#pragma unroll
      for (int i = 0; i < 4; ++i)
#pragma unroll
        for (int j = 0; j < 4; ++j)
          acc[i][j] = __builtin_amdgcn_mfma_f32_16x16x32_bf16(a[i], b[j], acc[i][j], 0, 0, 0);
    }
    __syncthreads();
  }

  int r0 = (l >> 4) * 4;
#pragma unroll
  for (int i = 0; i < 4; ++i) {
#pragma unroll
    for (int r = 0; r < 4; ++r) {
      int grow = m0 + wm * 64 + i * 16 + r0 + r;
#pragma unroll
      for (int j = 0; j < 4; ++j) {
        int gcol = n0 + wn * 64 + j * 16 + lr;
        size_t idx = (size_t)grow * N + gcol;
        float v = acc[i][j][r];
        if (EPI == 0) {
          ((ushort_t*)Cv)[idx] = f2bf(v);
        } else if (EPI == 1) {
          float r2 = ((const float*)resv)[idx];
          ((float*)Cv)[idx] = v + bias[gcol] + r2;
        } else {
          float g = bf2f(((const ushort_t*)resv)[idx]);
          ((ushort_t*)Cv)[idx] = f2bf(v * g / (1.0f + __expf(-g)));
        }
      }
    }
  }
}

// ---------------- MFMA flash attention ----------------
// Block = one (b,h) x 64 q-rows; 4 waves x 16 q-cols each. KV tiles of 64 keys.
// S^T = K·Q^T (A=K, B=Q) -> C-layout has q = lane&15 => per-lane softmax state.
// P^T via per-wave LDS tile (b64 writes / b128 reads). O^T += V^T·P^T (A=V^T swizzled).
#define LDP 72

__global__ __launch_bounds__(256) void attn_mfma(
    const ushort_t* __restrict__ Qp, const ushort_t* __restrict__ Kp,
    const ushort_t* __restrict__ Vp, ushort_t* __restrict__ Op) {
  __shared__ __align__(16) ushort_t Qs[64 * LDP];
  __shared__ __align__(16) ushort_t Ks[64 * LDP];
  __shared__ __align__(16) ushort_t Vs[64 * LDP];      // [dim][key ^ swz(dim)]
  __shared__ __align__(16) ushort_t Ps[4][16 * LDP];   // per-wave P^T[q][key]
  int tid = threadIdx.x;
  int l = tid & 63;
  int w = tid >> 6;
  int g = l >> 4;    // lane group 0..3
  int q = l & 15;    // q-col (and m-row index for A-frags)
  int h = blockIdx.y, b = blockIdx.z;
  int q0 = blockIdx.x * 64;
  const size_t base = (size_t)b * SEQ * DM + h * HDIM;

  // stage Q tile: 64 rows x 64 dims
#pragma unroll
  for (int i = 0; i < 2; ++i) {
    int cc = i * 256 + tid;
    int row = cc >> 3, d8 = (cc & 7) * 8;
    *(us8*)(&Qs[row * LDP + d8]) =
        *(const us8*)(Qp + base + (size_t)(q0 + row) * DM + d8);
  }

  float m_run = -3.0e38f, l_run = 0.f;
  f32x4 oacc[4] = {};   // frag t: dim = t*16 + g*4 + r, col q

  for (int kv = 0; kv < SEQ; kv += 64) {
    __syncthreads();  // prev iter's readers done (also covers Qs staging at kv=0)
#pragma unroll
    for (int i = 0; i < 2; ++i) {
      int cc = i * 256 + tid;
      int row = cc >> 3, d8 = (cc & 7) * 8;
      *(us8*)(&Ks[row * LDP + d8]) =
          *(const us8*)(Kp + base + (size_t)(kv + row) * DM + d8);
      us8 vv = *(const us8*)(Vp + base + (size_t)(kv + row) * DM + d8);
      int m8 = (d8 >> 3) & 7;
      int keysw = row ^ (m8 << 3);
#pragma unroll
      for (int j = 0; j < 8; ++j)
        Vs[(d8 + j) * LDP + keysw] = vv[j];
    }
    __syncthreads();

    // S^T tiles: m = key-tile t, n = q
    f32x4 sacc[4] = {};
#pragma unroll
    for (int kk = 0; kk < 2; ++kk) {
      bf16x8 qf = *(const bf16x8*)(&Qs[(w * 16 + q) * LDP + kk * 32 + g * 8]);
#pragma unroll
      for (int t = 0; t < 4; ++t) {
        bf16x8 kf = *(const bf16x8*)(&Ks[(t * 16 + q) * LDP + kk * 32 + g * 8]);
        sacc[t] = __builtin_amdgcn_mfma_f32_16x16x32_bf16(kf, qf, sacc[t], 0, 0, 0);
      }
    }

    // online softmax (per-lane q; keys: 16 in-lane + groups via shfl 16/32)
    float mt = -3.0e38f;
#pragma unroll
    for (int t = 0; t < 4; ++t)
#pragma unroll
      for (int r = 0; r < 4; ++r) mt = fmaxf(mt, sacc[t][r]);
    mt = fmaxf(mt, __shfl_xor(mt, 16));
    mt = fmaxf(mt, __shfl_xor(mt, 32));
    mt *= 0.125f;  // 1/sqrt(64)
    float m_new = fmaxf(m_run, mt);
    float alpha = __expf(m_run - m_new);
    float psum = 0.f;
#pragma unroll
    for (int t = 0; t < 4; ++t) {
      float p0 = __expf(fmaf(sacc[t][0], 0.125f, -m_new));
      float p1 = __expf(fmaf(sacc[t][1], 0.125f, -m_new));
      float p2 = __expf(fmaf(sacc[t][2], 0.125f, -m_new));
      float p3 = __expf(fmaf(sacc[t][3], 0.125f, -m_new));
      psum += (p0 + p1) + (p2 + p3);
      u32x2 d;
      d[0] = (unsigned int)f2bf(p0) | ((unsigned int)f2bf(p1) << 16);
      d[1] = (unsigned int)f2bf(p2) | ((unsigned int)f2bf(p3) << 16);
      *(u32x2*)(&Ps[w][q * LDP + t * 16 + g * 4]) = d;  // keys t*16+g*4..+3
    }
    m_run = m_new;
    l_run = l_run * alpha + psum;
#pragma unroll
    for (int t = 0; t < 4; ++t)
#pragma unroll
      for (int r = 0; r < 4; ++r) oacc[t][r] *= alpha;

    __asm__ volatile("s_waitcnt lgkmcnt(0)" ::: "memory");

    // O^T += V^T · P^T
#pragma unroll
    for (int kk = 0; kk < 2; ++kk) {
      bf16x8 pf = *(const bf16x8*)(&Ps[w][q * LDP + kk * 32 + g * 8]);
#pragma unroll
      for (int t = 0; t < 4; ++t) {
        int d = t * 16 + q;
        int keyoff = (kk * 32 + g * 8) ^ (((d >> 3) & 7) << 3);
        bf16x8 vf = *(const bf16x8*)(&Vs[d * LDP + keyoff]);
        oacc[t] = __builtin_amdgcn_mfma_f32_16x16x32_bf16(vf, pf, oacc[t], 0, 0, 0);
      }
    }
  }

  l_run += __shfl_xor(l_run, 16);
  l_run += __shfl_xor(l_run, 32);
  float inv = 1.f / l_run;
#pragma unroll
  for (int t = 0; t < 4; ++t) {
    us4 o;
#pragma unroll
    for (int r = 0; r < 4; ++r) o[r] = f2bf(oacc[t][r] * inv);
    *(us4*)(Op + base + (size_t)(q0 + w * 16 + q) * DM + t * 16 + g * 4) = o;
  }
}

// ---------------------------------------------------------------------------
// fp32 I/O; internals bf16 MFMA. Workspace (peak 72 MB):
//   [0,32M): bf16 weights; [32,40M): hb; [40,72M): qb/kb/vb/ab | gb overlay.
extern "C" void kernel_launch(void* const* d_in, const int* in_sizes, int n_in,
                              void* d_out, int out_size, void* d_ws, size_t ws_size,
                              hipStream_t stream) {
  const float* x   = (const float*)d_in[0];
  const float* Wq  = (const float*)d_in[1];
  const float* Wk  = (const float*)d_in[2];
  const float* Wv  = (const float*)d_in[3];
  const float* Wo  = (const float*)d_in[4];
  const float* bo  = (const float*)d_in[5];
  const float* anw = (const float*)d_in[6];
  const float* fnw = (const float*)d_in[7];
  const float* Wg  = (const float*)d_in[8];
  const float* Wh  = (const float*)d_in[9];
  const float* Wu  = (const float*)d_in[10];
  const float* bu  = (const float*)d_in[11];

  char* wsb = (char*)d_ws;
  ushort_t* Wqb = (ushort_t*)(wsb + 0);
  ushort_t* Wkb = (ushort_t*)(wsb + (2u << 20));
  ushort_t* Wvb = (ushort_t*)(wsb + (4u << 20));
  ushort_t* Wob = (ushort_t*)(wsb + (6u << 20));
  ushort_t* Wgb = (ushort_t*)(wsb + (8u << 20));
  ushort_t* Whb = (ushort_t*)(wsb + (16u << 20));
  ushort_t* Wub = (ushort_t*)(wsb + (24u << 20));
  ushort_t* hb  = (ushort_t*)(wsb + (32u << 20));
  ushort_t* qb  = (ushort_t*)(wsb + (40u << 20));
  ushort_t* kb  = (ushort_t*)(wsb + (48u << 20));
  ushort_t* vb  = (ushort_t*)(wsb + (56u << 20));
  ushort_t* ab  = (ushort_t*)(wsb + (64u << 20));
  ushort_t* gb  = (ushort_t*)(wsb + (40u << 20));  // overlays qb..ab (dead)
  float* out = (float*)d_out;

  f32_to_bf16<<<1024, 256, 0, stream>>>(Wq, Wqb, DM * DM);
  f32_to_bf16<<<1024, 256, 0, stream>>>(Wk, Wkb, DM * DM);
  f32_to_bf16<<<1024, 256, 0, stream>>>(Wv, Wvb, DM * DM);
  f32_to_bf16<<<1024, 256, 0, stream>>>(Wo, Wob, DM * DM);
  f32_to_bf16<<<4096, 256, 0, stream>>>(Wg, Wgb, DM * DH);
  f32_to_bf16<<<4096, 256, 0, stream>>>(Wh, Whb, DM * DH);
  f32_to_bf16<<<4096, 256, 0, stream>>>(Wu, Wub, DH * DM);

  // attn branch
  rmsnorm_kernel<<<ROWS, 256, 0, stream>>>(x, anw, hb);
  gemm_nt<0><<<dim3(8, 32), 256, 0, stream>>>(hb, Wqb, qb, ROWS, DM, DM, nullptr, nullptr);
  gemm_nt<0><<<dim3(8, 32), 256, 0, stream>>>(hb, Wkb, kb, ROWS, DM, DM, nullptr, nullptr);
  gemm_nt<0><<<dim3(8, 32), 256, 0, stream>>>(hb, Wvb, vb, ROWS, DM, DM, nullptr, nullptr);
  attn_mfma<<<dim3(SEQ / 64, NHEADS, NBATCH), 256, 0, stream>>>(qb, kb, vb, ab);
  // x2 = x + attn @ Wo + bo -> d_out (fp32)
  gemm_nt<1><<<dim3(8, 32), 256, 0, stream>>>(ab, Wob, out, ROWS, DM, DM, bo, x);

  // ffn branch
  rmsnorm_kernel<<<ROWS, 256, 0, stream>>>(out, fnw, hb);
  gemm_nt<0><<<dim3(32, 32), 256, 0, stream>>>(hb, Wgb, gb, ROWS, DH, DM, nullptr, nullptr);
  gemm_nt<2><<<dim3(32, 32), 256, 0, stream>>>(hb, Whb, gb, ROWS, DH, DM, nullptr, gb);
  gemm_nt<1><<<dim3(8, 32), 256, 0, stream>>>(gb, Wub, out, ROWS, DM, DH, bu, out);
}

// Round 6
// 509.092 us; speedup vs baseline: 4.0129x; 1.0524x over previous
//
#include <hip/hip_runtime.h>
#include <stdint.h>
#include <stddef.h>

typedef unsigned short ushort_t;
typedef __attribute__((ext_vector_type(8))) unsigned short us8;
typedef __attribute__((ext_vector_type(4))) unsigned short us4;
typedef __attribute__((ext_vector_type(2))) unsigned int u32x2;
typedef __attribute__((ext_vector_type(8))) short bf16x8;
typedef __attribute__((ext_vector_type(4))) float f32x4;
typedef __attribute__((ext_vector_type(4))) float f4;

#define DM 1024
#define SEQ 2048
#define NBATCH 2
#define NHEADS 16
#define HDIM 64
#define DH 4096
#define ROWS 4096  // NBATCH*SEQ

__device__ __forceinline__ float bf2f(ushort_t u) {
  union { unsigned int i; float f; } v; v.i = ((unsigned int)u) << 16; return v.f;
}
__device__ __forceinline__ ushort_t f2bf(float f) {
  union { float f; unsigned int i; } v; v.f = f;
  unsigned int x = v.i;
  unsigned int r = (x + 0x7FFFu + ((x >> 16) & 1u)) >> 16;  // RNE
  return (ushort_t)r;
}

// -------- fused fp32->bf16 + transpose: out[C x R](bf16) = in[R x C]^T --------
__global__ void transpose_f32_bf16(const float* __restrict__ in,
                                   ushort_t* __restrict__ out, int R, int C) {
  __shared__ ushort_t tile[64][68];
  int t = threadIdx.x;
  int c0 = blockIdx.x * 64, r0 = blockIdx.y * 64;
#pragma unroll
  for (int i = 0; i < 4; ++i) {
    int c = i * 256 + t;      // 0..1023
    int row = c >> 4;         // 0..63
    int col4 = (c & 15) * 4;  // 0..60
    f4 v = *(const f4*)(in + (size_t)(r0 + row) * C + c0 + col4);
#pragma unroll
    for (int j = 0; j < 4; ++j) tile[row][col4 + j] = f2bf(v[j]);
  }
  __syncthreads();
#pragma unroll
  for (int i = 0; i < 4; ++i) {
    int c = i * 256 + t;
    int orow = c >> 4;        // out row (= in col)
    int col4 = (c & 15) * 4;  // out cols (= in rows)
    us4 v;
#pragma unroll
    for (int j = 0; j < 4; ++j) v[j] = tile[col4 + j][orow];
    *(us4*)(out + (size_t)(c0 + orow) * R + r0 + col4) = v;
  }
}

// ---------------- RMSNorm: y = bf16( w * x * rsqrt(mean(x^2)+1e-6) ) ----------------
__global__ void rmsnorm_kernel(const float* __restrict__ x,
                               const float* __restrict__ w,
                               ushort_t* __restrict__ y) {
  int row = blockIdx.x;
  int t = threadIdx.x;
  f4 xv = *(const f4*)(x + (size_t)row * DM + t * 4);
  float s = 0.f;
#pragma unroll
  for (int j = 0; j < 4; ++j) s += xv[j] * xv[j];
#pragma unroll
  for (int off = 32; off >= 1; off >>= 1) s += __shfl_xor(s, off);
  __shared__ float wsum[4];
  if ((t & 63) == 0) wsum[t >> 6] = s;
  __syncthreads();
  float tot = wsum[0] + wsum[1] + wsum[2] + wsum[3];
  float scale = rsqrtf(tot * (1.0f / DM) + 1e-6f);
  f4 wv = *(const f4*)(w + t * 4);
  us4 o;
#pragma unroll
  for (int j = 0; j < 4; ++j) o[j] = f2bf(xv[j] * wv[j] * scale);
  *(us4*)(y + (size_t)row * DM + t * 4) = o;
}

// ---- MFMA bf16 GEMM (m97 structure): C[MxN] = A[MxK] @ Bt[NxK]^T ----
// Both operands staged via global_load_lds width=16 into UNPADDED 128x64 LDS
// (LDS offset == lane-order => satisfies wave-uniform-base constraint).
// EPI 0: C(bf16)=acc; 1: C(fp32)=acc+bias+res(fp32); 2: C(bf16)=silu(res(bf16))*acc
template <int EPI>
__global__ __launch_bounds__(256) void gemm_bt(
    const ushort_t* __restrict__ A, const ushort_t* __restrict__ Bt,
    void* __restrict__ Cv, int M, int N, int K,
    const float* __restrict__ bias, const void* __restrict__ resv) {
  __shared__ __align__(16) ushort_t As[128 * 64];
  __shared__ __align__(16) ushort_t Bs[128 * 64];
  int tid = threadIdx.x;
  int l = tid & 63, w = tid >> 6;
  int wm = w >> 1, wn = w & 1;
  int m0 = blockIdx.y * 128, n0 = blockIdx.x * 128;
  int lr = l & 15, lk = (l >> 4) * 8;
  f32x4 acc[4][4] = {};
  const ushort_t* Ag = A + (size_t)m0 * K;
  const ushort_t* Bg = Bt + (size_t)n0 * K;
  int srow = tid >> 3;            // 0..31
  int scol = (tid & 7) * 8;       // 0..56

  for (int kt = 0; kt < K; kt += 64) {
#pragma unroll
    for (int i = 0; i < 4; ++i) {
      int r2 = i * 32 + srow;
      int c = i * 256 + tid;
      __builtin_amdgcn_global_load_lds(
          (const __attribute__((address_space(1))) unsigned int*)(Ag + (size_t)r2 * K + kt + scol),
          (__attribute__((address_space(3))) unsigned int*)(&As[c * 8]), 16, 0, 0);
      __builtin_amdgcn_global_load_lds(
          (const __attribute__((address_space(1))) unsigned int*)(Bg + (size_t)r2 * K + kt + scol),
          (__attribute__((address_space(3))) unsigned int*)(&Bs[c * 8]), 16, 0, 0);
    }
    __syncthreads();
#pragma unroll
    for (int kk = 0; kk < 2; ++kk) {
      bf16x8 a[4], b[4];
#pragma unroll
      for (int i = 0; i < 4; ++i) {
        a[i] = *(const bf16x8*)(&As[(wm * 64 + i * 16 + lr) * 64 + kk * 32 + lk]);
        b[i] = *(const bf16x8*)(&Bs[(wn * 64 + i * 16 + lr) * 64 + kk * 32 + lk]);
      }
#pragma unroll
      for (int i = 0; i < 4; ++i)
#pragma unroll
        for (int j = 0; j < 4; ++j)
          acc[i][j] = __builtin_amdgcn_mfma_f32_16x16x32_bf16(a[i], b[j], acc[i][j], 0, 0, 0);
    }
    __syncthreads();
  }

  int r0 = (l >> 4) * 4;
#pragma unroll
  for (int i = 0; i < 4; ++i) {
#pragma unroll
    for (int r = 0; r < 4; ++r) {
      int grow = m0 + wm * 64 + i * 16 + r0 + r;
#pragma unroll
      for (int j = 0; j < 4; ++j) {
        int gcol = n0 + wn * 64 + j * 16 + lr;
        size_t idx = (size_t)grow * N + gcol;
        float v = acc[i][j][r];
        if (EPI == 0) {
          ((ushort_t*)Cv)[idx] = f2bf(v);
        } else if (EPI == 1) {
          float r2 = ((const float*)resv)[idx];
          ((float*)Cv)[idx] = v + bias[gcol] + r2;
        } else {
          float g = bf2f(((const ushort_t*)resv)[idx]);
          ((ushort_t*)Cv)[idx] = f2bf(v * g / (1.0f + __expf(-g)));
        }
      }
    }
  }
}

// ---------------- MFMA flash attention (fused-QKV input, stride qs) ----------------
#define LDP 72

__global__ __launch_bounds__(256) void attn_mfma(
    const ushort_t* __restrict__ Qp, const ushort_t* __restrict__ Kp,
    const ushort_t* __restrict__ Vp, ushort_t* __restrict__ Op,
    int qs, int os) {
  __shared__ __align__(16) ushort_t Qs[64 * LDP];
  __shared__ __align__(16) ushort_t Ks[64 * LDP];
  __shared__ __align__(16) ushort_t Vs[64 * LDP];      // [dim][key ^ swz(dim)]
  __shared__ __align__(16) ushort_t Ps[4][16 * LDP];   // per-wave P^T[q][key]
  int tid = threadIdx.x;
  int l = tid & 63;
  int w = tid >> 6;
  int g = l >> 4;
  int q = l & 15;
  int h = blockIdx.y, b = blockIdx.z;
  int q0 = blockIdx.x * 64;
  const size_t base = (size_t)b * SEQ * qs + h * HDIM;
  const size_t obase = (size_t)b * SEQ * os + h * HDIM;

#pragma unroll
  for (int i = 0; i < 2; ++i) {
    int cc = i * 256 + tid;
    int row = cc >> 3, d8 = (cc & 7) * 8;
    *(us8*)(&Qs[row * LDP + d8]) =
        *(const us8*)(Qp + base + (size_t)(q0 + row) * qs + d8);
  }

  float m_run = -3.0e38f, l_run = 0.f;
  f32x4 oacc[4] = {};

  for (int kv = 0; kv < SEQ; kv += 64) {
    __syncthreads();
#pragma unroll
    for (int i = 0; i < 2; ++i) {
      int cc = i * 256 + tid;
      int row = cc >> 3, d8 = (cc & 7) * 8;
      *(us8*)(&Ks[row * LDP + d8]) =
          *(const us8*)(Kp + base + (size_t)(kv + row) * qs + d8);
      us8 vv = *(const us8*)(Vp + base + (size_t)(kv + row) * qs + d8);
      int m8 = (d8 >> 3) & 7;
      int keysw = row ^ (m8 << 3);
#pragma unroll
      for (int j = 0; j < 8; ++j)
        Vs[(d8 + j) * LDP + keysw] = vv[j];
    }
    __syncthreads();

    f32x4 sacc[4] = {};
#pragma unroll
    for (int kk = 0; kk < 2; ++kk) {
      bf16x8 qf = *(const bf16x8*)(&Qs[(w * 16 + q) * LDP + kk * 32 + g * 8]);
#pragma unroll
      for (int t = 0; t < 4; ++t) {
        bf16x8 kf = *(const bf16x8*)(&Ks[(t * 16 + q) * LDP + kk * 32 + g * 8]);
        sacc[t] = __builtin_amdgcn_mfma_f32_16x16x32_bf16(kf, qf, sacc[t], 0, 0, 0);
      }
    }

    float mt = -3.0e38f;
#pragma unroll
    for (int t = 0; t < 4; ++t)
#pragma unroll
      for (int r = 0; r < 4; ++r) mt = fmaxf(mt, sacc[t][r]);
    mt = fmaxf(mt, __shfl_xor(mt, 16));
    mt = fmaxf(mt, __shfl_xor(mt, 32));
    mt *= 0.125f;
    float m_new = fmaxf(m_run, mt);
    float alpha = __expf(m_run - m_new);
    float psum = 0.f;
#pragma unroll
    for (int t = 0; t < 4; ++t) {
      float p0 = __expf(fmaf(sacc[t][0], 0.125f, -m_new));
      float p1 = __expf(fmaf(sacc[t][1], 0.125f, -m_new));
      float p2 = __expf(fmaf(sacc[t][2], 0.125f, -m_new));
      float p3 = __expf(fmaf(sacc[t][3], 0.125f, -m_new));
      psum += (p0 + p1) + (p2 + p3);
      u32x2 d;
      d[0] = (unsigned int)f2bf(p0) | ((unsigned int)f2bf(p1) << 16);
      d[1] = (unsigned int)f2bf(p2) | ((unsigned int)f2bf(p3) << 16);
      *(u32x2*)(&Ps[w][q * LDP + t * 16 + g * 4]) = d;
    }
    m_run = m_new;
    l_run = l_run * alpha + psum;
#pragma unroll
    for (int t = 0; t < 4; ++t)
#pragma unroll
      for (int r = 0; r < 4; ++r) oacc[t][r] *= alpha;

    __asm__ volatile("s_waitcnt lgkmcnt(0)" ::: "memory");

#pragma unroll
    for (int kk = 0; kk < 2; ++kk) {
      bf16x8 pf = *(const bf16x8*)(&Ps[w][q * LDP + kk * 32 + g * 8]);
#pragma unroll
      for (int t = 0; t < 4; ++t) {
        int d = t * 16 + q;
        int keyoff = (kk * 32 + g * 8) ^ (((d >> 3) & 7) << 3);
        bf16x8 vf = *(const bf16x8*)(&Vs[d * LDP + keyoff]);
        oacc[t] = __builtin_amdgcn_mfma_f32_16x16x32_bf16(vf, pf, oacc[t], 0, 0, 0);
      }
    }
  }

  l_run += __shfl_xor(l_run, 16);
  l_run += __shfl_xor(l_run, 32);
  float inv = 1.f / l_run;
#pragma unroll
  for (int t = 0; t < 4; ++t) {
    us4 o;
#pragma unroll
    for (int r = 0; r < 4; ++r) o[r] = f2bf(oacc[t][r] * inv);
    *(us4*)(Op + obase + (size_t)(q0 + w * 16 + q) * os + t * 16 + g * 4) = o;
  }
}

// ---------------------------------------------------------------------------
// fp32 I/O; internals bf16 MFMA, weights pre-transposed to N x K (fused w/
// fp32->bf16). Workspace (peak 72 MB):
//   [0,6M):   WqkvT (3072x1024)   [6,8M): WoT   [8,16M): WgT  [16,24M): WhT
//   [24,32M): WuT (1024x4096)     [32,40M): hb
//   [40,64M): qkvb (4096x3072)    [64,72M): ab  | phase2: gb @40M (32 MB)
extern "C" void kernel_launch(void* const* d_in, const int* in_sizes, int n_in,
                              void* d_out, int out_size, void* d_ws, size_t ws_size,
                              hipStream_t stream) {
  const float* x   = (const float*)d_in[0];
  const float* Wq  = (const float*)d_in[1];
  const float* Wk  = (const float*)d_in[2];
  const float* Wv  = (const float*)d_in[3];
  const float* Wo  = (const float*)d_in[4];
  const float* bo  = (const float*)d_in[5];
  const float* anw = (const float*)d_in[6];
  const float* fnw = (const float*)d_in[7];
  const float* Wg  = (const float*)d_in[8];
  const float* Wh  = (const float*)d_in[9];
  const float* Wu  = (const float*)d_in[10];
  const float* bu  = (const float*)d_in[11];

  char* wsb = (char*)d_ws;
  ushort_t* WqkvT = (ushort_t*)(wsb + 0);
  ushort_t* WoT   = (ushort_t*)(wsb + (6u << 20));
  ushort_t* WgT   = (ushort_t*)(wsb + (8u << 20));
  ushort_t* WhT   = (ushort_t*)(wsb + (16u << 20));
  ushort_t* WuT   = (ushort_t*)(wsb + (24u << 20));
  ushort_t* hb    = (ushort_t*)(wsb + (32u << 20));
  ushort_t* qkvb  = (ushort_t*)(wsb + (40u << 20));
  ushort_t* ab    = (ushort_t*)(wsb + (64u << 20));
  ushort_t* gb    = (ushort_t*)(wsb + (40u << 20));  // overlays qkvb/ab (dead)
  float* out = (float*)d_out;

  // weight transposes (fp32 K x N -> bf16 N x K)
  transpose_f32_bf16<<<dim3(16, 16), 256, 0, stream>>>(Wq, WqkvT, DM, DM);
  transpose_f32_bf16<<<dim3(16, 16), 256, 0, stream>>>(Wk, WqkvT + DM * DM, DM, DM);
  transpose_f32_bf16<<<dim3(16, 16), 256, 0, stream>>>(Wv, WqkvT + 2 * DM * DM, DM, DM);
  transpose_f32_bf16<<<dim3(16, 16), 256, 0, stream>>>(Wo, WoT, DM, DM);
  transpose_f32_bf16<<<dim3(64, 16), 256, 0, stream>>>(Wg, WgT, DM, DH);
  transpose_f32_bf16<<<dim3(64, 16), 256, 0, stream>>>(Wh, WhT, DM, DH);
  transpose_f32_bf16<<<dim3(16, 64), 256, 0, stream>>>(Wu, WuT, DH, DM);

  // attn branch
  rmsnorm_kernel<<<ROWS, 256, 0, stream>>>(x, anw, hb);
  gemm_bt<0><<<dim3(24, 32), 256, 0, stream>>>(hb, WqkvT, qkvb, ROWS, 3 * DM, DM, nullptr, nullptr);
  attn_mfma<<<dim3(SEQ / 64, NHEADS, NBATCH), 256, 0, stream>>>(
      qkvb, qkvb + DM, qkvb + 2 * DM, ab, 3 * DM, DM);
  gemm_bt<1><<<dim3(8, 32), 256, 0, stream>>>(ab, WoT, out, ROWS, DM, DM, bo, x);

  // ffn branch
  rmsnorm_kernel<<<ROWS, 256, 0, stream>>>(out, fnw, hb);
  gemm_bt<0><<<dim3(32, 32), 256, 0, stream>>>(hb, WgT, gb, ROWS, DH, DM, nullptr, nullptr);
  gemm_bt<2><<<dim3(32, 32), 256, 0, stream>>>(hb, WhT, gb, ROWS, DH, DM, nullptr, gb);
  gemm_bt<1><<<dim3(8, 32), 256, 0, stream>>>(gb, WuT, out, ROWS, DM, DH, bu, out);
}

// Round 7
// 482.367 us; speedup vs baseline: 4.2352x; 1.0554x over previous
//
#include <hip/hip_runtime.h>
#include <stdint.h>
#include <stddef.h>

typedef unsigned short ushort_t;
typedef __attribute__((ext_vector_type(8))) unsigned short us8;
typedef __attribute__((ext_vector_type(4))) unsigned short us4;
typedef __attribute__((ext_vector_type(2))) unsigned int u32x2;
typedef __attribute__((ext_vector_type(8))) short bf16x8;
typedef __attribute__((ext_vector_type(4))) float f32x4;
typedef __attribute__((ext_vector_type(4))) float f4;

#define DM 1024
#define SEQ 2048
#define NBATCH 2
#define NHEADS 16
#define HDIM 64
#define DH 4096
#define ROWS 4096  // NBATCH*SEQ

__device__ __forceinline__ float bf2f(ushort_t u) {
  union { unsigned int i; float f; } v; v.i = ((unsigned int)u) << 16; return v.f;
}
__device__ __forceinline__ ushort_t f2bf(float f) {
  union { float f; unsigned int i; } v; v.f = f;
  unsigned int x = v.i;
  unsigned int r = (x + 0x7FFFu + ((x >> 16) & 1u)) >> 16;  // RNE
  return (ushort_t)r;
}

// ---- all 7 weight transposes in ONE launch: out[C x R](bf16) = in[R x C]^T ----
__global__ void transpose_all(const float* __restrict__ Wq, const float* __restrict__ Wk,
                              const float* __restrict__ Wv, const float* __restrict__ Wo,
                              const float* __restrict__ Wg, const float* __restrict__ Wh,
                              const float* __restrict__ Wu,
                              ushort_t* __restrict__ WqkvT, ushort_t* __restrict__ WoT,
                              ushort_t* __restrict__ WgT, ushort_t* __restrict__ WhT,
                              ushort_t* __restrict__ WuT) {
  const float* src; ushort_t* dst; int R, C;
  switch (blockIdx.y) {
    case 0: src = Wq; dst = WqkvT;                R = DM; C = DM; break;
    case 1: src = Wk; dst = WqkvT + DM * DM;      R = DM; C = DM; break;
    case 2: src = Wv; dst = WqkvT + 2 * DM * DM;  R = DM; C = DM; break;
    case 3: src = Wo; dst = WoT;                  R = DM; C = DM; break;
    case 4: src = Wg; dst = WgT;                  R = DM; C = DH; break;
    case 5: src = Wh; dst = WhT;                  R = DM; C = DH; break;
    default: src = Wu; dst = WuT;                 R = DH; C = DM; break;
  }
  int nbx = C >> 6, nby = R >> 6;
  int bid = blockIdx.x;
  if (bid >= nbx * nby) return;
  int c0 = (bid % nbx) * 64, r0 = (bid / nbx) * 64;

  __shared__ ushort_t tile[64][68];
  int t = threadIdx.x;
#pragma unroll
  for (int i = 0; i < 4; ++i) {
    int c = i * 256 + t;
    int row = c >> 4, col4 = (c & 15) * 4;
    f4 v = *(const f4*)(src + (size_t)(r0 + row) * C + c0 + col4);
#pragma unroll
    for (int j = 0; j < 4; ++j) tile[row][col4 + j] = f2bf(v[j]);
  }
  __syncthreads();
#pragma unroll
  for (int i = 0; i < 4; ++i) {
    int c = i * 256 + t;
    int orow = c >> 4, col4 = (c & 15) * 4;
    us4 v;
#pragma unroll
    for (int j = 0; j < 4; ++j) v[j] = tile[col4 + j][orow];
    *(us4*)(dst + (size_t)(c0 + orow) * R + r0 + col4) = v;
  }
}

// ---------------- RMSNorm: y = bf16( w * x * rsqrt(mean(x^2)+1e-6) ) ----------------
__global__ void rmsnorm_kernel(const float* __restrict__ x,
                               const float* __restrict__ w,
                               ushort_t* __restrict__ y) {
  int row = blockIdx.x;
  int t = threadIdx.x;
  f4 xv = *(const f4*)(x + (size_t)row * DM + t * 4);
  float s = 0.f;
#pragma unroll
  for (int j = 0; j < 4; ++j) s += xv[j] * xv[j];
#pragma unroll
  for (int off = 32; off >= 1; off >>= 1) s += __shfl_xor(s, off);
  __shared__ float wsum[4];
  if ((t & 63) == 0) wsum[t >> 6] = s;
  __syncthreads();
  float tot = wsum[0] + wsum[1] + wsum[2] + wsum[3];
  float scale = rsqrtf(tot * (1.0f / DM) + 1e-6f);
  f4 wv = *(const f4*)(w + t * 4);
  us4 o;
#pragma unroll
  for (int j = 0; j < 4; ++j) o[j] = f2bf(xv[j] * wv[j] * scale);
  *(us4*)(y + (size_t)row * DM + t * 4) = o;
}

// ---- MFMA bf16 GEMM (m97 structure): C[MxN] = A[MxK] @ Bt[NxK]^T ----
// TM = M-tile (128 or 64). N-tile fixed 128. global_load_lds width=16 staging.
// EPI 0: C(bf16)=acc; 1: C(fp32)=acc+bias+res(fp32); 2: C(bf16)=silu(res(bf16))*acc
template <int EPI, int TM>
__global__ __launch_bounds__(256) void gemm_bt(
    const ushort_t* __restrict__ A, const ushort_t* __restrict__ Bt,
    void* __restrict__ Cv, int M, int N, int K,
    const float* __restrict__ bias, const void* __restrict__ resv) {
  constexpr int FI = TM / 32;  // m-frags per wave
  __shared__ __align__(16) ushort_t As[TM * 64];
  __shared__ __align__(16) ushort_t Bs[128 * 64];
  int tid = threadIdx.x;
  int l = tid & 63, w = tid >> 6;
  int wm = w >> 1, wn = w & 1;
  int m0 = blockIdx.y * TM, n0 = blockIdx.x * 128;
  int lr = l & 15, lk = (l >> 4) * 8;
  f32x4 acc[FI][4] = {};
  const ushort_t* Ag = A + (size_t)m0 * K;
  const ushort_t* Bg = Bt + (size_t)n0 * K;
  int srow = tid >> 3;            // 0..31
  int scol = (tid & 7) * 8;       // 0..56

  for (int kt = 0; kt < K; kt += 64) {
#pragma unroll
    for (int i = 0; i < TM / 32; ++i) {
      __builtin_amdgcn_global_load_lds(
          (const __attribute__((address_space(1))) unsigned int*)(Ag + (size_t)(i * 32 + srow) * K + kt + scol),
          (__attribute__((address_space(3))) unsigned int*)(&As[(i * 256 + tid) * 8]), 16, 0, 0);
    }
#pragma unroll
    for (int i = 0; i < 4; ++i) {
      __builtin_amdgcn_global_load_lds(
          (const __attribute__((address_space(1))) unsigned int*)(Bg + (size_t)(i * 32 + srow) * K + kt + scol),
          (__attribute__((address_space(3))) unsigned int*)(&Bs[(i * 256 + tid) * 8]), 16, 0, 0);
    }
    __syncthreads();
#pragma unroll
    for (int kk = 0; kk < 2; ++kk) {
      bf16x8 a[FI], b[4];
#pragma unroll
      for (int i = 0; i < FI; ++i)
        a[i] = *(const bf16x8*)(&As[(wm * (TM / 2) + i * 16 + lr) * 64 + kk * 32 + lk]);
#pragma unroll
      for (int j = 0; j < 4; ++j)
        b[j] = *(const bf16x8*)(&Bs[(wn * 64 + j * 16 + lr) * 64 + kk * 32 + lk]);
#pragma unroll
      for (int i = 0; i < FI; ++i)
#pragma unroll
        for (int j = 0; j < 4; ++j)
          acc[i][j] = __builtin_amdgcn_mfma_f32_16x16x32_bf16(a[i], b[j], acc[i][j], 0, 0, 0);
    }
    __syncthreads();
  }

  int r0 = (l >> 4) * 4;
#pragma unroll
  for (int i = 0; i < FI; ++i) {
#pragma unroll
    for (int r = 0; r < 4; ++r) {
      int grow = m0 + wm * (TM / 2) + i * 16 + r0 + r;
#pragma unroll
      for (int j = 0; j < 4; ++j) {
        int gcol = n0 + wn * 64 + j * 16 + lr;
        size_t idx = (size_t)grow * N + gcol;
        float v = acc[i][j][r];
        if (EPI == 0) {
          ((ushort_t*)Cv)[idx] = f2bf(v);
        } else if (EPI == 1) {
          float r2 = ((const float*)resv)[idx];
          ((float*)Cv)[idx] = v + bias[gcol] + r2;
        } else {
          float g = bf2f(((const ushort_t*)resv)[idx]);
          ((ushort_t*)Cv)[idx] = f2bf(v * g / (1.0f + __expf(-g)));
        }
      }
    }
  }
}

// ---- V transpose: VT[b][h][d][seq] = V (qkvb cols 2048..3071) ----
__global__ void vtrans_kernel(const ushort_t* __restrict__ qkv,
                              ushort_t* __restrict__ VT) {
  __shared__ ushort_t tile[64][72];
  int t = threadIdx.x;
  int s0 = blockIdx.x * 64;
  int h = blockIdx.y, b = blockIdx.z;
  const ushort_t* src = qkv + (size_t)b * SEQ * (3 * DM) + 2 * DM + h * HDIM;
  ushort_t* dst = VT + ((size_t)(b * NHEADS + h) * HDIM) * SEQ;
#pragma unroll
  for (int i = 0; i < 2; ++i) {
    int c = i * 256 + t;
    int srow = c >> 3, d8 = (c & 7) * 8;
    *(us8*)(&tile[srow][d8]) = *(const us8*)(src + (size_t)(s0 + srow) * (3 * DM) + d8);
  }
  __syncthreads();
#pragma unroll
  for (int i = 0; i < 2; ++i) {
    int c = i * 256 + t;
    int drow = c >> 3, s8 = (c & 7) * 8;
    us8 v;
#pragma unroll
    for (int j = 0; j < 8; ++j) v[j] = tile[s8 + j][drow];
    *(us8*)(dst + (size_t)drow * SEQ + s0 + s8) = v;
  }
}

// ---------------- MFMA flash attention (fused-QKV input; V pre-transposed) ----------------
#define LDP 72

__global__ __launch_bounds__(256) void attn_mfma(
    const ushort_t* __restrict__ Qp, const ushort_t* __restrict__ Kp,
    const ushort_t* __restrict__ VT, ushort_t* __restrict__ Op,
    int qs, int os) {
  __shared__ __align__(16) ushort_t Qs[64 * LDP];
  __shared__ __align__(16) ushort_t Ks[64 * LDP];
  __shared__ __align__(16) ushort_t Vs[64 * LDP];      // [dim][key], no swizzle
  __shared__ __align__(16) ushort_t Ps[4][16 * LDP];   // per-wave P^T[q][key]
  int tid = threadIdx.x;
  int l = tid & 63;
  int w = tid >> 6;
  int g = l >> 4;
  int q = l & 15;
  int h = blockIdx.y, b = blockIdx.z;
  int q0 = blockIdx.x * 64;
  const size_t base = (size_t)b * SEQ * qs + h * HDIM;
  const size_t obase = (size_t)b * SEQ * os + h * HDIM;
  const ushort_t* Vb = VT + ((size_t)(b * NHEADS + h) * HDIM) * SEQ;

#pragma unroll
  for (int i = 0; i < 2; ++i) {
    int cc = i * 256 + tid;
    int row = cc >> 3, d8 = (cc & 7) * 8;
    *(us8*)(&Qs[row * LDP + d8]) =
        *(const us8*)(Qp + base + (size_t)(q0 + row) * qs + d8);
  }

  float m_run = -3.0e38f, l_run = 0.f;
  f32x4 oacc[4] = {};

  for (int kv = 0; kv < SEQ; kv += 64) {
    __syncthreads();
#pragma unroll
    for (int i = 0; i < 2; ++i) {
      int cc = i * 256 + tid;
      int row = cc >> 3, d8 = (cc & 7) * 8;
      *(us8*)(&Ks[row * LDP + d8]) =
          *(const us8*)(Kp + base + (size_t)(kv + row) * qs + d8);
      *(us8*)(&Vs[row * LDP + d8]) =
          *(const us8*)(Vb + (size_t)row * SEQ + kv + d8);  // row=dim, d8=key
    }
    __syncthreads();

    f32x4 sacc[4] = {};
#pragma unroll
    for (int kk = 0; kk < 2; ++kk) {
      bf16x8 qf = *(const bf16x8*)(&Qs[(w * 16 + q) * LDP + kk * 32 + g * 8]);
#pragma unroll
      for (int t = 0; t < 4; ++t) {
        bf16x8 kf = *(const bf16x8*)(&Ks[(t * 16 + q) * LDP + kk * 32 + g * 8]);
        sacc[t] = __builtin_amdgcn_mfma_f32_16x16x32_bf16(kf, qf, sacc[t], 0, 0, 0);
      }
    }

    float mt = -3.0e38f;
#pragma unroll
    for (int t = 0; t < 4; ++t)
#pragma unroll
      for (int r = 0; r < 4; ++r) mt = fmaxf(mt, sacc[t][r]);
    mt = fmaxf(mt, __shfl_xor(mt, 16));
    mt = fmaxf(mt, __shfl_xor(mt, 32));
    mt *= 0.125f;
    float m_new = fmaxf(m_run, mt);
    float alpha = __expf(m_run - m_new);
    float psum = 0.f;
#pragma unroll
    for (int t = 0; t < 4; ++t) {
      float p0 = __expf(fmaf(sacc[t][0], 0.125f, -m_new));
      float p1 = __expf(fmaf(sacc[t][1], 0.125f, -m_new));
      float p2 = __expf(fmaf(sacc[t][2], 0.125f, -m_new));
      float p3 = __expf(fmaf(sacc[t][3], 0.125f, -m_new));
      psum += (p0 + p1) + (p2 + p3);
      u32x2 d;
      d[0] = (unsigned int)f2bf(p0) | ((unsigned int)f2bf(p1) << 16);
      d[1] = (unsigned int)f2bf(p2) | ((unsigned int)f2bf(p3) << 16);
      *(u32x2*)(&Ps[w][q * LDP + t * 16 + g * 4]) = d;
    }
    m_run = m_new;
    l_run = l_run * alpha + psum;
#pragma unroll
    for (int t = 0; t < 4; ++t)
#pragma unroll
      for (int r = 0; r < 4; ++r) oacc[t][r] *= alpha;

    __asm__ volatile("s_waitcnt lgkmcnt(0)" ::: "memory");

#pragma unroll
    for (int kk = 0; kk < 2; ++kk) {
      bf16x8 pf = *(const bf16x8*)(&Ps[w][q * LDP + kk * 32 + g * 8]);
#pragma unroll
      for (int t = 0; t < 4; ++t) {
        bf16x8 vf = *(const bf16x8*)(&Vs[(t * 16 + q) * LDP + kk * 32 + g * 8]);
        oacc[t] = __builtin_amdgcn_mfma_f32_16x16x32_bf16(vf, pf, oacc[t], 0, 0, 0);
      }
    }
  }

  l_run += __shfl_xor(l_run, 16);
  l_run += __shfl_xor(l_run, 32);
  float inv = 1.f / l_run;
#pragma unroll
  for (int t = 0; t < 4; ++t) {
    us4 o;
#pragma unroll
    for (int r = 0; r < 4; ++r) o[r] = f2bf(oacc[t][r] * inv);
    *(us4*)(Op + obase + (size_t)(q0 + w * 16 + q) * os + t * 16 + g * 4) = o;
  }
}

// ---------------------------------------------------------------------------
// fp32 I/O; internals bf16 MFMA. ws peak 72 MB:
//   [0,6): WqkvT  [6,8): WoT  [8,16): WgT  [16,24): WhT  [24,32): WuT
//   [32,40): hb   [40,64): qkvb   [64,72): ab | phase2: gb @40 (32 MB)
// VT (16 MB) lives in d_out, which is free until O-proj writes x2 there.
extern "C" void kernel_launch(void* const* d_in, const int* in_sizes, int n_in,
                              void* d_out, int out_size, void* d_ws, size_t ws_size,
                              hipStream_t stream) {
  const float* x   = (const float*)d_in[0];
  const float* Wq  = (const float*)d_in[1];
  const float* Wk  = (const float*)d_in[2];
  const float* Wv  = (const float*)d_in[3];
  const float* Wo  = (const float*)d_in[4];
  const float* bo  = (const float*)d_in[5];
  const float* anw = (const float*)d_in[6];
  const float* fnw = (const float*)d_in[7];
  const float* Wg  = (const float*)d_in[8];
  const float* Wh  = (const float*)d_in[9];
  const float* Wu  = (const float*)d_in[10];
  const float* bu  = (const float*)d_in[11];

  char* wsb = (char*)d_ws;
  ushort_t* WqkvT = (ushort_t*)(wsb + 0);
  ushort_t* WoT   = (ushort_t*)(wsb + (6u << 20));
  ushort_t* WgT   = (ushort_t*)(wsb + (8u << 20));
  ushort_t* WhT   = (ushort_t*)(wsb + (16u << 20));
  ushort_t* WuT   = (ushort_t*)(wsb + (24u << 20));
  ushort_t* hb    = (ushort_t*)(wsb + (32u << 20));
  ushort_t* qkvb  = (ushort_t*)(wsb + (40u << 20));
  ushort_t* ab    = (ushort_t*)(wsb + (64u << 20));
  ushort_t* gb    = (ushort_t*)(wsb + (40u << 20));  // overlays qkvb/ab (dead)
  ushort_t* VT    = (ushort_t*)d_out;                 // scratch until O-proj
  float* out = (float*)d_out;

  transpose_all<<<dim3(1024, 7), 256, 0, stream>>>(Wq, Wk, Wv, Wo, Wg, Wh, Wu,
                                                   WqkvT, WoT, WgT, WhT, WuT);

  // attn branch
  rmsnorm_kernel<<<ROWS, 256, 0, stream>>>(x, anw, hb);
  gemm_bt<0, 128><<<dim3(24, 32), 256, 0, stream>>>(hb, WqkvT, qkvb, ROWS, 3 * DM, DM, nullptr, nullptr);
  vtrans_kernel<<<dim3(SEQ / 64, NHEADS, NBATCH), 256, 0, stream>>>(qkvb, VT);
  attn_mfma<<<dim3(SEQ / 64, NHEADS, NBATCH), 256, 0, stream>>>(
      qkvb, qkvb + DM, VT, ab, 3 * DM, DM);
  gemm_bt<1, 64><<<dim3(8, 64), 256, 0, stream>>>(ab, WoT, out, ROWS, DM, DM, bo, x);

  // ffn branch
  rmsnorm_kernel<<<ROWS, 256, 0, stream>>>(out, fnw, hb);
  gemm_bt<0, 128><<<dim3(32, 32), 256, 0, stream>>>(hb, WgT, gb, ROWS, DH, DM, nullptr, nullptr);
  gemm_bt<2, 128><<<dim3(32, 32), 256, 0, stream>>>(hb, WhT, gb, ROWS, DH, DM, nullptr, gb);
  gemm_bt<1, 64><<<dim3(8, 64), 256, 0, stream>>>(gb, WuT, out, ROWS, DM, DH, bu, out);
}